// Round 10
// baseline (460.816 us; speedup 1.0000x reference)
//
#include <hip/hip_runtime.h>
#include <hip/hip_bf16.h>
#include <math.h>

#define NDOC 4
#define SEQL 1024
#define HIDD 768
#define NHEADS 12
#define NEENT 48
#define NMEN 4
#define NPAIR 1000
#define NLAB 97
#define GHID 500
#define NEDGE 897
#define NROW (NDOC*NPAIR)

// bilinear GEMM geometry
#define KBIL 49152            // 12 c-chunks * 4096
#define KSTEPS_MAIN 1536      // KBIL/32
#define KSTEPS_TOT 1540       // + 4 tail steps (128 k for logits_lab, padded)
#define NPAD 128              // 97 -> 128 cols
#define NPOUT 112             // stored partial width
#define NCHUNK 24             // (c, j-half) chunks
#define BM 128                // bilinear M-tile
#define NMT 32                // ceil(4000/128) with 4096-row buffers
#define NMT64 63              // ceil(4000/64) M-tiles for ht2

// prep_all block section sizes (order: G0, WPREP, SEQ, EMB, ATT, WHT)
#define PB_G0    388
#define PB_WPREP 3080
#define PB_SEQ   1536
#define PB_EMB   192
#define PB_ATT   2304
#define PB_WHT   1152
#define PB_TOT   (PB_G0+PB_WPREP+PB_SEQ+PB_EMB+PB_ATT+PB_WHT)

typedef __attribute__((ext_vector_type(8))) short short8v;
typedef __attribute__((ext_vector_type(4))) short short4v;
typedef __attribute__((ext_vector_type(4))) float f32x4;
typedef _Float16 half8v __attribute__((ext_vector_type(8)));
typedef unsigned int uint4v __attribute__((ext_vector_type(4)));

__device__ __forceinline__ unsigned short f2bfbits(float x) {
    return __builtin_bit_cast(unsigned short, __float2bfloat16(x));
}
__device__ __forceinline__ float bf2f(short b) {
    return __builtin_bit_cast(float, ((unsigned int)(unsigned short)b) << 16);
}

__device__ __forceinline__ float block_reduce_sum(float v, float* red) {
    int tid = threadIdx.x;
    red[tid] = v;
    __syncthreads();
    for (int s = blockDim.x >> 1; s > 0; s >>= 1) {
        if (tid < s) red[tid] += red[tid + s];
        __syncthreads();
    }
    float r = red[0];
    __syncthreads();
    return r;
}

__device__ __forceinline__ float block_reduce_max(float v, float* red) {
    int tid = threadIdx.x;
    red[tid] = v;
    __syncthreads();
    for (int s = blockDim.x >> 1; s > 0; s >>= 1) {
        if (tid < s) red[tid] = fmaxf(red[tid], red[tid + s]);
        __syncthreads();
    }
    float r = red[0];
    __syncthreads();
    return r;
}

// ---------------- fused input-only preps + GAT L0 GEMM ------------------------
__global__ void __launch_bounds__(256) k_prep_all(
    const float* __restrict__ label_emb, const float* __restrict__ gat_W0,
    float* __restrict__ feat0,
    const float* __restrict__ bil_W, _Float16* __restrict__ Wb,
    const float* __restrict__ seq, __hip_bfloat16* __restrict__ seqb,
    const int* __restrict__ mstarts, float* __restrict__ ent_emb,
    const float* __restrict__ att, __hip_bfloat16* __restrict__ ent_attb,
    const float* __restrict__ head_W, __hip_bfloat16* __restrict__ Whb,
    const float* __restrict__ tail_W, __hip_bfloat16* __restrict__ Wtb)
{
    int bid = blockIdx.x;
    if (bid < PB_G0) {
        int n = bid >> 2, jt = bid & 3;
        int j = jt * 256 + threadIdx.x;
        if (j < 1000) {
            const float* a = label_emb + (size_t)n * 768;
            float a0=0.f,a1=0.f,a2=0.f,a3=0.f,a4=0.f,a5=0.f,a6=0.f,a7=0.f;
            for (int k = 0; k < 768; k += 8) {
                a0 += a[k+0] * gat_W0[(size_t)(k+0)*1000 + j];
                a1 += a[k+1] * gat_W0[(size_t)(k+1)*1000 + j];
                a2 += a[k+2] * gat_W0[(size_t)(k+2)*1000 + j];
                a3 += a[k+3] * gat_W0[(size_t)(k+3)*1000 + j];
                a4 += a[k+4] * gat_W0[(size_t)(k+4)*1000 + j];
                a5 += a[k+5] * gat_W0[(size_t)(k+5)*1000 + j];
                a6 += a[k+6] * gat_W0[(size_t)(k+6)*1000 + j];
                a7 += a[k+7] * gat_W0[(size_t)(k+7)*1000 + j];
            }
            feat0[(size_t)n*1000 + j] = ((a0+a1)+(a2+a3))+((a4+a5)+(a6+a7));
        }
        return;
    }
    bid -= PB_G0;
    if (bid < PB_WPREP) {
        int t = bid * 256 + threadIdx.x;
        int lane = t & 63;
        int nt = (t >> 6) & 7;
        int kt = t >> 9;
        int col = nt * 16 + (lane & 15);
        int kbase = kt * 32 + ((lane >> 4) << 3);
        half8v v;
        #pragma unroll
        for (int e = 0; e < 8; ++e) {
            int k = kbase + e;
            float x = (col < NLAB && k < (KBIL + NLAB)) ? bil_W[(size_t)k * NLAB + col] : 0.f;
            v[e] = (_Float16)x;
        }
        ((half8v*)Wb)[t] = v;
        return;
    }
    bid -= PB_WPREP;
    if (bid < PB_SEQ) {
        int t = bid * 256 + threadIdx.x;
        int lane = t & 63;
        int rest = t >> 6;
        int dt = rest % 48; rest /= 48;
        int kt = rest % 32;
        int doc = rest / 32;
        int d = dt * 16 + (lane & 15);
        int kbase = kt * 32 + ((lane >> 4) << 3);
        short8v v;
        #pragma unroll
        for (int e = 0; e < 8; ++e)
            v[e] = (short)f2bfbits(seq[((size_t)doc * SEQL + kbase + e) * HIDD + d]);
        ((short8v*)seqb)[t] = v;
        return;
    }
    bid -= PB_SEQ;
    if (bid < PB_EMB) {
        int be = bid;
        int b = be / NEENT;
        int pos[NMEN];
        #pragma unroll
        for (int m = 0; m < NMEN; ++m) pos[m] = mstarts[be * NMEN + m] + 1;
        for (int d = threadIdx.x; d < HIDD; d += 256) {
            float v0 = seq[((size_t)b * SEQL + pos[0]) * HIDD + d];
            float v1 = seq[((size_t)b * SEQL + pos[1]) * HIDD + d];
            float v2 = seq[((size_t)b * SEQL + pos[2]) * HIDD + d];
            float v3 = seq[((size_t)b * SEQL + pos[3]) * HIDD + d];
            float mx = fmaxf(fmaxf(v0, v1), fmaxf(v2, v3));
            float s = expf(v0 - mx) + expf(v1 - mx) + expf(v2 - mx) + expf(v3 - mx);
            ent_emb[(size_t)be * HIDD + d] = mx + logf(s);
        }
        return;
    }
    bid -= PB_EMB;
    if (bid < PB_ATT) {
        int idx = bid;
        int h = idx % NHEADS;
        int be = idx / NHEADS;
        int b = be / NEENT;
        int pos[NMEN];
        #pragma unroll
        for (int m = 0; m < NMEN; ++m) pos[m] = mstarts[be * NMEN + m] + 1;
        const float* abase = att + ((size_t)b * NHEADS + h) * SEQL * SEQL;
        for (int s = threadIdx.x; s < SEQL; s += 256) {
            float acc = 0.f;
            #pragma unroll
            for (int m = 0; m < NMEN; ++m) acc += abase[(size_t)pos[m] * SEQL + s];
            ent_attb[(size_t)idx * SEQL + s] = __float2bfloat16(acc * 0.25f);
        }
        return;
    }
    bid -= PB_ATT;
    {
        const float* W = bid < 576 ? head_W : tail_W;
        __hip_bfloat16* Wf = bid < 576 ? Whb : Wtb;
        int t = (bid % 576) * 256 + threadIdx.x;    // over 48*48*64 = 147456
        int lane = t & 63;
        int ntile = (t >> 6) % 48;
        int kt = t / (48 * 64);
        int col = ntile * 16 + (lane & 15);
        int kbase = kt * 32 + ((lane >> 4) << 3);
        short8v v;
        #pragma unroll
        for (int e = 0; e < 8; ++e)
            v[e] = (short)f2bfbits(W[(size_t)(kbase + e) * HIDD + col]);
        ((short8v*)Wf)[t] = v;
    }
}

// ---------------- small GEMM, parallel over (row, jtile): C = A @ W -----------
template<int K, int N>
__global__ void __launch_bounds__(256) k_gemm2(
    const float* __restrict__ A, const float* __restrict__ W, float* __restrict__ C)
{
    const int JT = (N + 255) / 256;
    int n  = blockIdx.x / JT;
    int jt = blockIdx.x % JT;
    int j = jt * 256 + threadIdx.x;
    if (j >= N) return;
    const float* a = A + (size_t)n * K;
    float acc0 = 0.f, acc1 = 0.f, acc2 = 0.f, acc3 = 0.f;
    float acc4 = 0.f, acc5 = 0.f, acc6 = 0.f, acc7 = 0.f;
    for (int k = 0; k < K; k += 8) {
        acc0 += a[k + 0] * W[(size_t)(k + 0) * N + j];
        acc1 += a[k + 1] * W[(size_t)(k + 1) * N + j];
        acc2 += a[k + 2] * W[(size_t)(k + 2) * N + j];
        acc3 += a[k + 3] * W[(size_t)(k + 3) * N + j];
        acc4 += a[k + 4] * W[(size_t)(k + 4) * N + j];
        acc5 += a[k + 5] * W[(size_t)(k + 5) * N + j];
        acc6 += a[k + 6] * W[(size_t)(k + 6) * N + j];
        acc7 += a[k + 7] * W[(size_t)(k + 7) * N + j];
    }
    C[(size_t)n * N + j] = ((acc0 + acc1) + (acc2 + acc3)) + ((acc4 + acc5) + (acc6 + acc7));
}

// ---------------- GAT attention scalars el/er ----------------
template<int NH, int OD>
__global__ void k_eler(const float* __restrict__ feat, const float* __restrict__ al,
                       const float* __restrict__ ar, float* __restrict__ el,
                       float* __restrict__ er)
{
    __shared__ float red[256];
    int n = blockIdx.x;
    for (int h = 0; h < NH; ++h) {
        float a = 0.f, b = 0.f;
        for (int k = threadIdx.x; k < OD; k += blockDim.x) {
            float f = feat[(size_t)n * NH * OD + h * OD + k];
            a += f * al[h * OD + k];
            b += f * ar[h * OD + k];
        }
        float sa = block_reduce_sum(a, red);
        float sb = block_reduce_sum(b, red);
        if (threadIdx.x == 0) { el[n * NH + h] = sa; er[n * NH + h] = sb; }
    }
}

// ---------------- GAT edge-softmax aggregation (one block per dst node) -------
template<int NH, int OD, int QN, int DO_ELU, int WLT>
__global__ void k_gat_agg(const float* __restrict__ feat,
                          const float* __restrict__ el, const float* __restrict__ er,
                          const int* __restrict__ esrc, const int* __restrict__ edst,
                          const float* __restrict__ bias, float* __restrict__ out,
                          float* __restrict__ labT)
{
    __shared__ float red[256];
    __shared__ int ss[NEDGE];
    __shared__ int dd[NEDGE];
    int n = blockIdx.x;
    for (int t = threadIdx.x; t < NEDGE; t += blockDim.x) { ss[t] = esrc[t]; dd[t] = edst[t]; }
    __syncthreads();
    float ern[NH], emax[NH], den[NH];
    #pragma unroll
    for (int h = 0; h < NH; ++h) ern[h] = er[n * NH + h];
    #pragma unroll
    for (int h = 0; h < NH; ++h) {
        float mx = -1e30f;
        for (int t = threadIdx.x; t < NEDGE; t += blockDim.x) {
            if (dd[t] == n) {
                float x = el[ss[t] * NH + h] + ern[h];
                x = x > 0.f ? x : 0.2f * x;
                mx = fmaxf(mx, x);
            }
        }
        emax[h] = block_reduce_max(mx, red);
        float sm = 0.f;
        for (int t = threadIdx.x; t < NEDGE; t += blockDim.x) {
            if (dd[t] == n) {
                float x = el[ss[t] * NH + h] + ern[h];
                x = x > 0.f ? x : 0.2f * x;
                sm += expf(x - emax[h]);
            }
        }
        den[h] = block_reduce_sum(sm, red);
    }
    float acc[QN];
    #pragma unroll
    for (int q = 0; q < QN; ++q) acc[q] = 0.f;
    for (int t = 0; t < NEDGE; ++t) {
        if (dd[t] != n) continue;
        int s = ss[t];
        float alpha[NH];
        #pragma unroll
        for (int h = 0; h < NH; ++h) {
            float x = el[s * NH + h] + ern[h];
            x = x > 0.f ? x : 0.2f * x;
            alpha[h] = expf(x - emax[h]) / (den[h] + 1e-9f);
        }
        #pragma unroll
        for (int q = 0; q < QN; ++q) {
            int idx = threadIdx.x + q * 256;
            if (idx < NH * OD) {
                int h = idx / OD;
                acc[q] += alpha[h] * feat[(size_t)s * NH * OD + idx];
            }
        }
    }
    #pragma unroll
    for (int q = 0; q < QN; ++q) {
        int idx = threadIdx.x + q * 256;
        if (idx < NH * OD) {
            float v = acc[q] + bias[idx];
            float o = DO_ELU ? (v > 0.f ? v : expm1f(v)) : v;
            out[(size_t)n * NH * OD + idx] = o;
            if (WLT) labT[(size_t)idx * NLAB + n] = o;
        }
    }
}

// ---------------- per-entity: EL = lnorm(ent_emb @ lab.T); F/G = EL @ lin2 ----
__global__ void __launch_bounds__(128) k_entlab(
    const float* __restrict__ ent_emb, const float* __restrict__ labT,
    const float* __restrict__ ln_g, const float* __restrict__ ln_b,
    const float* __restrict__ lin2_W,
    float* __restrict__ F, float* __restrict__ G)
{
    __shared__ float e[HIDD];
    __shared__ float red[128];
    __shared__ float elsh[NLAB];
    int be = blockIdx.x;                          // 0..191
    for (int k = threadIdx.x; k < HIDD; k += 128) e[k] = ent_emb[(size_t)be * HIDD + k];
    __syncthreads();
    int l = threadIdx.x;
    float a = 0.f;
    if (l < NLAB)
        for (int k = 0; k < HIDD; ++k) a += e[k] * labT[k * NLAB + l];
    float v = (l < NLAB) ? a : 0.f;
    float s  = block_reduce_sum(v, red);
    float s2 = block_reduce_sum(v * v, red);
    const float invL = 1.0f / NLAB;
    float mu = s * invL;
    float var = s2 * invL - mu * mu;
    float is = 1.0f / sqrtf(var + 1e-5f);
    if (l < NLAB) elsh[l] = (a - mu) * is * ln_g[l] + ln_b[l];
    __syncthreads();
    if (l < NLAB) {
        float f = 0.f, g = 0.f;
        for (int q = 0; q < NLAB; ++q) {
            float eq = elsh[q];
            f += eq * lin2_W[q * NLAB + l];
            g += eq * lin2_W[(NLAB + q) * NLAB + l];
        }
        F[be * NLAB + l] = f;
        G[be * NLAB + l] = g;
    }
}

// ---------------- ht rows -> bf16 HT; + emb_bf; + llhf gather -----------------
__global__ void __launch_bounds__(256) k_ht(
    const __hip_bfloat16* __restrict__ ent_attb, const int* __restrict__ hts,
    __hip_bfloat16* __restrict__ HTb,
    const float* __restrict__ ent_emb, __hip_bfloat16* __restrict__ emb_bf,
    const float* __restrict__ F, const float* __restrict__ G,
    const float* __restrict__ lin2_b, _Float16* __restrict__ llhf)
{
    __shared__ float red[256];
    int bid = blockIdx.x;
    if (bid >= NROW + 72) {
        // llhf gather: llhf[n,l] = F[h-ent,l] + G[t-ent,l] + lin2_b[l]
        int t = (bid - NROW - 72) * 256 + threadIdx.x;   // over 4000*128
        int n = t >> 7, l = t & 127;
        float v = 0.f;
        if (l < NLAB) {
            int b = n / NPAIR;
            int hi = hts[n * 2], ti = hts[n * 2 + 1];
            v = F[(b * NEENT + hi) * NLAB + l] + G[(b * NEENT + ti) * NLAB + l] + lin2_b[l];
        }
        llhf[t] = (_Float16)v;
        return;
    }
    if (bid >= NROW) {
        // ent_emb f32 -> bf16 row-major (72 blocks)
        int t = (bid - NROW) * 256 + threadIdx.x;   // over 18432
        const float4* p = (const float4*)(ent_emb + (size_t)t * 8);
        float4 a = p[0], b = p[1];
        short8v v;
        v[0] = (short)f2bfbits(a.x); v[1] = (short)f2bfbits(a.y);
        v[2] = (short)f2bfbits(a.z); v[3] = (short)f2bfbits(a.w);
        v[4] = (short)f2bfbits(b.x); v[5] = (short)f2bfbits(b.y);
        v[6] = (short)f2bfbits(b.z); v[7] = (short)f2bfbits(b.w);
        ((short8v*)emb_bf)[t] = v;
        return;
    }
    int n = (bid & 7) * 500 + (bid >> 3);        // XCD-group
    int b = n / NPAIR;
    int hi = hts[n * 2], ti = hts[n * 2 + 1];
    const __hip_bfloat16* ha = ent_attb + ((size_t)(b * NEENT + hi)) * NHEADS * SEQL;
    const __hip_bfloat16* ta = ent_attb + ((size_t)(b * NEENT + ti)) * NHEADS * SEQL;
    int s0 = threadIdx.x * 4;
    float4 acc = {0.f, 0.f, 0.f, 0.f};
    #pragma unroll
    for (int h = 0; h < NHEADS; ++h) {
        short4v a4 = *(const short4v*)&ha[h * SEQL + s0];
        short4v t4 = *(const short4v*)&ta[h * SEQL + s0];
        acc.x += bf2f(a4.x) * bf2f(t4.x);
        acc.y += bf2f(a4.y) * bf2f(t4.y);
        acc.z += bf2f(a4.z) * bf2f(t4.z);
        acc.w += bf2f(a4.w) * bf2f(t4.w);
    }
    const float inv12 = 1.0f / NHEADS;
    acc.x *= inv12; acc.y *= inv12; acc.z *= inv12; acc.w *= inv12;
    float Z = block_reduce_sum(acc.x + acc.y + acc.z + acc.w, red);
    float scale = 1.0f / (Z + 1e-5f);
    int nloc = n % NPAIR;
    short4v v;
    v.x = (short)f2bfbits(acc.x * scale);
    v.y = (short)f2bfbits(acc.y * scale);
    v.z = (short)f2bfbits(acc.z * scale);
    v.w = (short)f2bfbits(acc.w * scale);
    *(short4v*)&HTb[((size_t)b * 1024 + nloc) * SEQL + s0] = v;
}

// ---------------- rs = HT @ seq per doc via MFMA -> bf16 rsb (B prefetch) -----
__global__ void __launch_bounds__(256) k_rs_mfma(
    const __hip_bfloat16* __restrict__ HTb, const __hip_bfloat16* __restrict__ seqb,
    __hip_bfloat16* __restrict__ rsb)
{
    int b = blockIdx.x;
    int wg = (b & 7) * 96 + (b >> 3);           // doc-grouped per XCD
    int doc = wg / 192;
    int rem = wg % 192;
    int mtile = rem / 6, ngrp = rem % 6;
    int tid = threadIdx.x, wave = tid >> 6, lane = tid & 63;
    int mh = wave & 1, ng = wave >> 1;
    int lr = lane & 15, lg = lane >> 4;
    int rowl = mtile * 32 + mh * 16 + lr;
    const short8v* av = (const short8v*)(HTb + (((size_t)doc * 1024 + rowl) * SEQL));
    const short8v* bv = (const short8v*)seqb;
    int dtbase = ngrp * 8 + ng * 4;
    f32x4 acc[4];
    #pragma unroll
    for (int nt = 0; nt < 4; ++nt) acc[nt] = f32x4{0.f, 0.f, 0.f, 0.f};
    const short8v* wp0 = bv + ((((size_t)doc * 32) * 48 + dtbase) * 64 + lane);
    short8v bc[4];
    #pragma unroll
    for (int nt = 0; nt < 4; ++nt) bc[nt] = wp0[nt * 64];
    short8v ac = av[lg];
    for (int kt = 0; kt < 32; ++kt) {
        int ktn = kt < 31 ? kt + 1 : 31;
        const short8v* wpn = bv + ((((size_t)doc * 32 + ktn) * 48 + dtbase) * 64 + lane);
        short8v bn[4];
        #pragma unroll
        for (int nt = 0; nt < 4; ++nt) bn[nt] = wpn[nt * 64];
        short8v an = av[ktn * 4 + lg];
        #pragma unroll
        for (int nt = 0; nt < 4; ++nt)
            acc[nt] = __builtin_amdgcn_mfma_f32_16x16x32_bf16(ac, bc[nt], acc[nt], 0, 0, 0);
        ac = an;
        #pragma unroll
        for (int nt = 0; nt < 4; ++nt) bc[nt] = bn[nt];
    }
    #pragma unroll
    for (int nt = 0; nt < 4; ++nt) {
        int d = ngrp * 128 + ng * 64 + nt * 16 + lr;
        #pragma unroll
        for (int r = 0; r < 4; ++r) {
            int nloc = mtile * 32 + mh * 16 + lg * 4 + r;
            if (nloc < NPAIR)
                rsb[((size_t)(doc * NPAIR + nloc)) * HIDD + d] = __float2bfloat16(acc[nt][r]);
        }
    }
}

// ---------------- head+tail GEMM via MFMA, M=64, A+B prefetch -----------------
__global__ void __launch_bounds__(256) k_ht2_mfma(
    const __hip_bfloat16* __restrict__ emb_bf, const __hip_bfloat16* __restrict__ rsb,
    const int* __restrict__ hts,
    const __hip_bfloat16* __restrict__ Whb, const __hip_bfloat16* __restrict__ Wtb,
    const float* __restrict__ head_b, const float* __restrict__ tail_b,
    float* __restrict__ h2, float* __restrict__ t2)
{
    int bid = blockIdx.x;
    int which = bid >= (NMT64 * 6) ? 1 : 0;
    int rem = bid - which * (NMT64 * 6);
    int mtile = rem / 6, ngrp = rem % 6;
    int tid = threadIdx.x, wave = tid >> 6, lane = tid & 63;
    int ng = wave & 1, mp = wave >> 1;
    int lr = lane & 15, lg = lane >> 4;
    int na = mtile * 64 + mp * 32 + lr;
    int nb = na + 16;
    int nac = na < NROW ? na : NROW - 1;
    int nbc = nb < NROW ? nb : NROW - 1;
    int ba = nac / NPAIR, bb = nbc / NPAIR;
    int enta = hts[nac * 2 + which];
    int entb = hts[nbc * 2 + which];
    const short8v* embrow_a = (const short8v*)emb_bf + (size_t)(ba * NEENT + enta) * 96;
    const short8v* embrow_b = (const short8v*)emb_bf + (size_t)(bb * NEENT + entb) * 96;
    const short8v* rsrow_a  = (const short8v*)rsb + (size_t)nac * 96;
    const short8v* rsrow_b  = (const short8v*)rsb + (size_t)nbc * 96;
    const short8v* wv = (const short8v*)(which ? Wtb : Whb);
    const float* bias = which ? tail_b : head_b;
    float* out = which ? t2 : h2;
    f32x4 acc[2][4];
    #pragma unroll
    for (int m = 0; m < 2; ++m)
        #pragma unroll
        for (int nt = 0; nt < 4; ++nt) acc[m][nt] = f32x4{0.f, 0.f, 0.f, 0.f};
    int ntbase = ngrp * 8 + ng * 4;
    short8v aca = embrow_a[lg], acb = embrow_b[lg];
    const short8v* wp0 = wv + ((size_t)(0 * 48 + ntbase) * 64 + lane);
    short8v bc[4];
    #pragma unroll
    for (int nt = 0; nt < 4; ++nt) bc[nt] = wp0[nt * 64];
    for (int kt = 0; kt < 48; ++kt) {
        int ktn = kt < 47 ? kt + 1 : 47;
        const short8v* pa = ktn < 24 ? embrow_a + ktn * 4 : rsrow_a + (ktn - 24) * 4;
        const short8v* pb = ktn < 24 ? embrow_b + ktn * 4 : rsrow_b + (ktn - 24) * 4;
        short8v ana = pa[lg];
        short8v anb = pb[lg];
        const short8v* wpn = wv + (((size_t)ktn * 48 + ntbase) * 64 + lane);
        short8v bn[4];
        #pragma unroll
        for (int nt = 0; nt < 4; ++nt) bn[nt] = wpn[nt * 64];
        #pragma unroll
        for (int nt = 0; nt < 4; ++nt) {
            acc[0][nt] = __builtin_amdgcn_mfma_f32_16x16x32_bf16(aca, bc[nt], acc[0][nt], 0, 0, 0);
            acc[1][nt] = __builtin_amdgcn_mfma_f32_16x16x32_bf16(acb, bc[nt], acc[1][nt], 0, 0, 0);
        }
        aca = ana; acb = anb;
        #pragma unroll
        for (int nt = 0; nt < 4; ++nt) bc[nt] = bn[nt];
    }
    #pragma unroll
    for (int m = 0; m < 2; ++m) {
        #pragma unroll
        for (int nt = 0; nt < 4; ++nt) {
            int col = ngrp * 128 + ng * 64 + nt * 16 + lr;
            float bj = bias[col];
            #pragma unroll
            for (int r = 0; r < 4; ++r) {
                int n2 = mtile * 64 + mp * 32 + m * 16 + lg * 4 + r;
                if (n2 < NROW)
                    out[(size_t)n2 * HIDD + col] = tanhf(acc[m][nt][r] + bj);
            }
        }
    }
}

// ---------------- bilinear fp16 MFMA, M=128, 24 (c, j-half) chunks ------------
// grid 768 = 32 mtiles(128 rows) x 24 chunks; wave: ng = w&1, mp = w>>1
// each wave: 4 A-frags (rows mp*64 + 16m) x 4 B-frags -> 16 MFMAs per 4 B-loads
__global__ void __launch_bounds__(256) k_bilin_mfma(
    const float* __restrict__ h2, const float* __restrict__ t2,
    const _Float16* __restrict__ llhf, const _Float16* __restrict__ Wb,
    float* __restrict__ pout)
{
    __shared__ unsigned int hs2[BM * 68];   // {h,h} packed fp16 (all 64 i)
    __shared__ _Float16 ts[BM * 40];        // fp16 t, this j-half (32 + pad 8)
    int bid = blockIdx.x;
    int chunk = bid % NCHUNK;        // 0..23
    int mtile = bid / NCHUNK;        // 0..31
    int c  = chunk >> 1;
    int jh = chunk & 1;
    int j0 = jh * 32;
    int n0 = mtile * BM;
    int tid = threadIdx.x;
    int wave = tid >> 6, lane = tid & 63;
    int ng = wave & 1, mp = wave >> 1;
    int lr = lane & 15;
    int lg = lane >> 4;
    int koff = lg << 3;
    int row0 = mp * 64 + lr;         // frags at row0 + 16*m, m=0..3
    f32x4 acc[4][4];
    #pragma unroll
    for (int m = 0; m < 4; ++m)
        #pragma unroll
        for (int nt = 0; nt < 4; ++nt) acc[m][nt] = f32x4{0.f, 0.f, 0.f, 0.f};

    const half8v* wbv = (const half8v*)Wb;

    for (int idx = tid; idx < BM * 64; idx += 256) {
        int r = idx >> 6, cc = idx & 63;
        float hv = h2[(size_t)(n0 + r) * HIDD + c * 64 + cc];
        unsigned short hb = __builtin_bit_cast(unsigned short, (_Float16)hv);
        hs2[r * 68 + cc] = ((unsigned int)hb << 16) | hb;
    }
    for (int idx = tid; idx < BM * 32; idx += 256) {
        int r = idx >> 5, cc = idx & 31;
        ts[r * 40 + cc] = (_Float16)t2[(size_t)(n0 + r) * HIDD + c * 64 + j0 + cc];
    }
    __syncthreads();

    half8v tv[4];
    #pragma unroll
    for (int m = 0; m < 4; ++m)
        tv[m] = *(const half8v*)&ts[(row0 + 16 * m) * 40 + koff];
    int ktbase = c * 128 + jh;
    const half8v* wpb = wbv + (((size_t)ktbase * 8 + ng * 4) * 64 + lane);  // +i*1024
    half8v bc[4];
    #pragma unroll
    for (int nt = 0; nt < 4; ++nt) bc[nt] = wpb[nt * 64];
    for (int i = 0; i < 64; ++i) {
        int in = i < 63 ? i + 1 : 63;
        const half8v* wpn = wpb + (size_t)in * 1024;
        half8v bn[4];
        #pragma unroll
        for (int nt = 0; nt < 4; ++nt) bn[nt] = wpn[nt * 64];
        half8v af[4];
        #pragma unroll
        for (int m = 0; m < 4; ++m) {
            unsigned int hh = hs2[(row0 + 16 * m) * 68 + i];
            af[m] = __builtin_bit_cast(half8v, uint4v{hh, hh, hh, hh}) * tv[m];
        }
        #pragma unroll
        for (int nt = 0; nt < 4; ++nt) {
            #pragma unroll
            for (int m = 0; m < 4; ++m)
                acc[m][nt] = __builtin_amdgcn_mfma_f32_16x16x32_f16(af[m], bc[nt], acc[m][nt], 0, 0, 0);
        }
        #pragma unroll
        for (int nt = 0; nt < 4; ++nt) bc[nt] = bn[nt];
    }
    if (chunk == NCHUNK - 1) {
        const half8v* lv = (const half8v*)llhf;
        #pragma unroll
        for (int tt = 0; tt < 4; ++tt) {
            int kt = KSTEPS_MAIN + tt;
            const half8v* wp = wbv + (((size_t)kt * 8 + ng * 4) * 64 + lane);
            half8v bf[4];
            #pragma unroll
            for (int nt = 0; nt < 4; ++nt) bf[nt] = wp[nt * 64];
            #pragma unroll
            for (int m = 0; m < 4; ++m) {
                half8v afm = lv[(size_t)(n0 + row0 + 16 * m) * 16 + tt * 4 + lg];
                #pragma unroll
                for (int nt = 0; nt < 4; ++nt)
                    acc[m][nt] = __builtin_amdgcn_mfma_f32_16x16x32_f16(afm, bf[nt], acc[m][nt], 0, 0, 0);
            }
        }
    }
    #pragma unroll
    for (int m = 0; m < 4; ++m) {
        #pragma unroll
        for (int nt = 0; nt < 4; ++nt) {
            int col = ng * 64 + nt * 16 + lr;
            if (col < NPOUT) {
                #pragma unroll
                for (int r = 0; r < 4; ++r) {
                    int rown = n0 + mp * 64 + m * 16 + lg * 4 + r;
                    if (rown < NROW)
                        pout[((size_t)chunk * NROW + rown) * NPOUT + col] = acc[m][nt][r];
                }
            }
        }
    }
}

// ---------------- reduce partials + bias -> out -------------------------------
__global__ void k_bilin_reduce(const float* __restrict__ pout,
                               const float* __restrict__ bil_b,
                               float* __restrict__ out)
{
    int t = blockIdx.x * 256 + threadIdx.x;
    if (t >= NROW * NLAB) return;
    int n = t / NLAB, l = t - n * NLAB;
    float a = bil_b[l];
    #pragma unroll
    for (int q = 0; q < NCHUNK; ++q) a += pout[((size_t)q * NROW + n) * NPOUT + l];
    out[t] = a;
}

extern "C" void kernel_launch(void* const* d_in, const int* in_sizes, int n_in,
                              void* d_out, int out_size, void* d_ws, size_t ws_size,
                              hipStream_t stream)
{
    (void)in_sizes; (void)n_in; (void)out_size; (void)ws_size;
    const float* seq       = (const float*)d_in[0];
    const float* att       = (const float*)d_in[1];
    const int*   mstarts   = (const int*)d_in[2];
    const int*   hts       = (const int*)d_in[4];
    const float* label_emb = (const float*)d_in[5];
    const float* gat_W0    = (const float*)d_in[6];
    const float* gat_al0   = (const float*)d_in[7];
    const float* gat_ar0   = (const float*)d_in[8];
    const float* gat_b0    = (const float*)d_in[9];
    const float* gat_W1    = (const float*)d_in[10];
    const float* gat_al1   = (const float*)d_in[11];
    const float* gat_ar1   = (const float*)d_in[12];
    const float* gat_b1    = (const float*)d_in[13];
    const int*   esrc      = (const int*)d_in[14];
    const int*   edst      = (const int*)d_in[15];
    const float* head_W    = (const float*)d_in[16];
    const float* head_b    = (const float*)d_in[17];
    const float* tail_W    = (const float*)d_in[18];
    const float* tail_b    = (const float*)d_in[19];
    const float* ln_g      = (const float*)d_in[20];
    const float* ln_b      = (const float*)d_in[21];
    const float* lin2_W    = (const float*)d_in[22];
    const float* lin2_b    = (const float*)d_in[23];
    const float* bil_W     = (const float*)d_in[24];
    const float* bil_b     = (const float*)d_in[25];
    float* out = (float*)d_out;

    // ws layout: no overlays, 64B-aligned
    float* p = (float*)d_ws;
    auto alloc = [&](size_t n) { float* r = p; p += ((n + 15) & ~(size_t)15); return r; };
    float* ent_emb = alloc(147456);
    float* F       = alloc(18624);
    float* G       = alloc(18624);
    float* labT    = alloc(74496);
    float* feat0   = alloc(97000);
    float* el0     = alloc(200);
    float* er0     = alloc(200);
    float* h0      = alloc(97000);
    float* feat1   = alloc(74496);
    float* el1     = alloc(104);
    float* er1     = alloc(104);
    float* lab     = alloc(74496);
    float* h2      = alloc((size_t)4096 * 768);
    float* t2      = alloc((size_t)4096 * 768);
    float* pout    = alloc((size_t)NCHUNK * NROW * NPOUT);
    __hip_bfloat16* ent_attb = (__hip_bfloat16*)alloc(1179648);  // 2359296 bf16
    __hip_bfloat16* HTb    = (__hip_bfloat16*)alloc(2097152);
    __hip_bfloat16* seqb   = (__hip_bfloat16*)alloc(1572864);
    __hip_bfloat16* rsb    = (__hip_bfloat16*)alloc(1536000);
    __hip_bfloat16* Whb    = (__hip_bfloat16*)alloc(589824);
    __hip_bfloat16* Wtb    = (__hip_bfloat16*)alloc(589824);
    __hip_bfloat16* emb_bf = (__hip_bfloat16*)alloc(73728);
    _Float16* llhf = (_Float16*)alloc(262144);   // 4096 x 128 fp16
    _Float16* Wb   = (_Float16*)alloc(3153920);

    // 1. all input-only preps + GAT L0 GEMM
    k_prep_all<<<PB_TOT, 256, 0, stream>>>(
        label_emb, gat_W0, feat0, bil_W, Wb, seq, seqb, mstarts, ent_emb,
        att, ent_attb, head_W, Whb, tail_W, Wtb);

    // GAT chain
    k_eler<2, 500><<<NLAB, 256, 0, stream>>>(feat0, gat_al0, gat_ar0, el0, er0);
    k_gat_agg<2, 500, 4, 1, 0><<<NLAB, 256, 0, stream>>>(feat0, el0, er0, esrc, edst, gat_b0, h0, nullptr);
    k_gemm2<1000, 768><<<NLAB * 3, 256, 0, stream>>>(h0, gat_W1, feat1);
    k_eler<1, 768><<<NLAB, 256, 0, stream>>>(feat1, gat_al1, gat_ar1, el1, er1);
    k_gat_agg<1, 768, 3, 0, 1><<<NLAB, 256, 0, stream>>>(feat1, el1, er1, esrc, edst, gat_b1, lab, labT);

    // per-entity label logits: lnorm + F/G in one kernel
    k_entlab<<<NDOC * NEENT, 128, 0, stream>>>(ent_emb, labT, ln_g, ln_b, lin2_W, F, G);

    // ht rows + emb_bf + llhf gather (2000 blocks) in one kernel
    k_ht<<<NROW + 72 + 2000, 256, 0, stream>>>(ent_attb, hts, HTb, ent_emb, emb_bf,
                                               F, G, lin2_b, llhf);

    k_rs_mfma<<<768, 256, 0, stream>>>(HTb, seqb, rsb);

    k_ht2_mfma<<<2 * NMT64 * 6, 256, 0, stream>>>(emb_bf, rsb, hts, Whb, Wtb, head_b, tail_b, h2, t2);

    k_bilin_mfma<<<NMT * NCHUNK, 256, 0, stream>>>(h2, t2, llhf, Wb, pout);
    k_bilin_reduce<<<(NROW * NLAB + 255) / 256, 256, 0, stream>>>(pout, bil_b, out);
}

// Round 11
// 460.013 us; speedup vs baseline: 1.0017x; 1.0017x over previous
//
#include <hip/hip_runtime.h>
#include <hip/hip_bf16.h>
#include <math.h>

#define NDOC 4
#define SEQL 1024
#define HIDD 768
#define NHEADS 12
#define NEENT 48
#define NMEN 4
#define NPAIR 1000
#define NLAB 97
#define GHID 500
#define NEDGE 897
#define NROW (NDOC*NPAIR)

// bilinear GEMM geometry
#define KBIL 49152            // 12 c-chunks * 4096
#define KSTEPS_MAIN 1536      // KBIL/32
#define KSTEPS_TOT 1540       // + 4 tail steps (128 k for logits_lab, padded)
#define NPAD 128              // 97 -> 128 cols
#define NPOUT 112             // stored partial width
#define NCHUNK 24             // (c, j-half) chunks
#define BM 128                // bilinear M-tile
#define NMT 32                // ceil(4000/128) with 4096-row buffers
#define NMT64 63              // ceil(4000/64) M-tiles for ht2

// prep_all block section sizes (order: G0, WPREP, SEQ, EMB, ATT, WHT)
#define PB_G0    388
#define PB_WPREP 3080
#define PB_SEQ   1536
#define PB_EMB   192
#define PB_ATT   2304
#define PB_WHT   1152
#define PB_TOT   (PB_G0+PB_WPREP+PB_SEQ+PB_EMB+PB_ATT+PB_WHT)

typedef __attribute__((ext_vector_type(8))) short short8v;
typedef __attribute__((ext_vector_type(4))) short short4v;
typedef __attribute__((ext_vector_type(4))) float f32x4;
typedef _Float16 half8v __attribute__((ext_vector_type(8)));
typedef unsigned int uint4v __attribute__((ext_vector_type(4)));

__device__ __forceinline__ unsigned short f2bfbits(float x) {
    return __builtin_bit_cast(unsigned short, __float2bfloat16(x));
}
__device__ __forceinline__ float bf2f(short b) {
    return __builtin_bit_cast(float, ((unsigned int)(unsigned short)b) << 16);
}

__device__ __forceinline__ float block_reduce_sum(float v, float* red) {
    int tid = threadIdx.x;
    red[tid] = v;
    __syncthreads();
    for (int s = blockDim.x >> 1; s > 0; s >>= 1) {
        if (tid < s) red[tid] += red[tid + s];
        __syncthreads();
    }
    float r = red[0];
    __syncthreads();
    return r;
}

__device__ __forceinline__ float block_reduce_max(float v, float* red) {
    int tid = threadIdx.x;
    red[tid] = v;
    __syncthreads();
    for (int s = blockDim.x >> 1; s > 0; s >>= 1) {
        if (tid < s) red[tid] = fmaxf(red[tid], red[tid + s]);
        __syncthreads();
    }
    float r = red[0];
    __syncthreads();
    return r;
}

// ---------------- fused input-only preps + GAT L0 GEMM ------------------------
__global__ void __launch_bounds__(256) k_prep_all(
    const float* __restrict__ label_emb, const float* __restrict__ gat_W0,
    float* __restrict__ feat0,
    const float* __restrict__ bil_W, _Float16* __restrict__ Wb,
    const float* __restrict__ seq, __hip_bfloat16* __restrict__ seqb,
    const int* __restrict__ mstarts, float* __restrict__ ent_emb,
    const float* __restrict__ att, __hip_bfloat16* __restrict__ ent_attb,
    const float* __restrict__ head_W, __hip_bfloat16* __restrict__ Whb,
    const float* __restrict__ tail_W, __hip_bfloat16* __restrict__ Wtb)
{
    int bid = blockIdx.x;
    if (bid < PB_G0) {
        int n = bid >> 2, jt = bid & 3;
        int j = jt * 256 + threadIdx.x;
        if (j < 1000) {
            const float* a = label_emb + (size_t)n * 768;
            float a0=0.f,a1=0.f,a2=0.f,a3=0.f,a4=0.f,a5=0.f,a6=0.f,a7=0.f;
            for (int k = 0; k < 768; k += 8) {
                a0 += a[k+0] * gat_W0[(size_t)(k+0)*1000 + j];
                a1 += a[k+1] * gat_W0[(size_t)(k+1)*1000 + j];
                a2 += a[k+2] * gat_W0[(size_t)(k+2)*1000 + j];
                a3 += a[k+3] * gat_W0[(size_t)(k+3)*1000 + j];
                a4 += a[k+4] * gat_W0[(size_t)(k+4)*1000 + j];
                a5 += a[k+5] * gat_W0[(size_t)(k+5)*1000 + j];
                a6 += a[k+6] * gat_W0[(size_t)(k+6)*1000 + j];
                a7 += a[k+7] * gat_W0[(size_t)(k+7)*1000 + j];
            }
            feat0[(size_t)n*1000 + j] = ((a0+a1)+(a2+a3))+((a4+a5)+(a6+a7));
        }
        return;
    }
    bid -= PB_G0;
    if (bid < PB_WPREP) {
        int t = bid * 256 + threadIdx.x;
        int lane = t & 63;
        int nt = (t >> 6) & 7;
        int kt = t >> 9;
        int col = nt * 16 + (lane & 15);
        int kbase = kt * 32 + ((lane >> 4) << 3);
        half8v v;
        #pragma unroll
        for (int e = 0; e < 8; ++e) {
            int k = kbase + e;
            float x = (col < NLAB && k < (KBIL + NLAB)) ? bil_W[(size_t)k * NLAB + col] : 0.f;
            v[e] = (_Float16)x;
        }
        ((half8v*)Wb)[t] = v;
        return;
    }
    bid -= PB_WPREP;
    if (bid < PB_SEQ) {
        int t = bid * 256 + threadIdx.x;
        int lane = t & 63;
        int rest = t >> 6;
        int dt = rest % 48; rest /= 48;
        int kt = rest % 32;
        int doc = rest / 32;
        int d = dt * 16 + (lane & 15);
        int kbase = kt * 32 + ((lane >> 4) << 3);
        short8v v;
        #pragma unroll
        for (int e = 0; e < 8; ++e)
            v[e] = (short)f2bfbits(seq[((size_t)doc * SEQL + kbase + e) * HIDD + d]);
        ((short8v*)seqb)[t] = v;
        return;
    }
    bid -= PB_SEQ;
    if (bid < PB_EMB) {
        int be = bid;
        int b = be / NEENT;
        int pos[NMEN];
        #pragma unroll
        for (int m = 0; m < NMEN; ++m) pos[m] = mstarts[be * NMEN + m] + 1;
        for (int d = threadIdx.x; d < HIDD; d += 256) {
            float v0 = seq[((size_t)b * SEQL + pos[0]) * HIDD + d];
            float v1 = seq[((size_t)b * SEQL + pos[1]) * HIDD + d];
            float v2 = seq[((size_t)b * SEQL + pos[2]) * HIDD + d];
            float v3 = seq[((size_t)b * SEQL + pos[3]) * HIDD + d];
            float mx = fmaxf(fmaxf(v0, v1), fmaxf(v2, v3));
            float s = expf(v0 - mx) + expf(v1 - mx) + expf(v2 - mx) + expf(v3 - mx);
            ent_emb[(size_t)be * HIDD + d] = mx + logf(s);
        }
        return;
    }
    bid -= PB_EMB;
    if (bid < PB_ATT) {
        int idx = bid;
        int h = idx % NHEADS;
        int be = idx / NHEADS;
        int b = be / NEENT;
        int pos[NMEN];
        #pragma unroll
        for (int m = 0; m < NMEN; ++m) pos[m] = mstarts[be * NMEN + m] + 1;
        const float* abase = att + ((size_t)b * NHEADS + h) * SEQL * SEQL;
        int s0 = threadIdx.x * 4;                  // 256 threads x float4 = 1024
        float4 acc = {0.f, 0.f, 0.f, 0.f};
        #pragma unroll
        for (int m = 0; m < NMEN; ++m) {
            float4 a = *(const float4*)&abase[(size_t)pos[m] * SEQL + s0];
            acc.x += a.x; acc.y += a.y; acc.z += a.z; acc.w += a.w;
        }
        short4v v;
        v.x = (short)f2bfbits(acc.x * 0.25f);
        v.y = (short)f2bfbits(acc.y * 0.25f);
        v.z = (short)f2bfbits(acc.z * 0.25f);
        v.w = (short)f2bfbits(acc.w * 0.25f);
        *(short4v*)&ent_attb[(size_t)idx * SEQL + s0] = v;
        return;
    }
    bid -= PB_ATT;
    {
        const float* W = bid < 576 ? head_W : tail_W;
        __hip_bfloat16* Wf = bid < 576 ? Whb : Wtb;
        int t = (bid % 576) * 256 + threadIdx.x;    // over 48*48*64 = 147456
        int lane = t & 63;
        int ntile = (t >> 6) % 48;
        int kt = t / (48 * 64);
        int col = ntile * 16 + (lane & 15);
        int kbase = kt * 32 + ((lane >> 4) << 3);
        short8v v;
        #pragma unroll
        for (int e = 0; e < 8; ++e)
            v[e] = (short)f2bfbits(W[(size_t)(kbase + e) * HIDD + col]);
        ((short8v*)Wf)[t] = v;
    }
}

// ---------------- small GEMM, parallel over (row, jtile): C = A @ W -----------
template<int K, int N>
__global__ void __launch_bounds__(256) k_gemm2(
    const float* __restrict__ A, const float* __restrict__ W, float* __restrict__ C)
{
    const int JT = (N + 255) / 256;
    int n  = blockIdx.x / JT;
    int jt = blockIdx.x % JT;
    int j = jt * 256 + threadIdx.x;
    if (j >= N) return;
    const float* a = A + (size_t)n * K;
    float acc0 = 0.f, acc1 = 0.f, acc2 = 0.f, acc3 = 0.f;
    float acc4 = 0.f, acc5 = 0.f, acc6 = 0.f, acc7 = 0.f;
    for (int k = 0; k < K; k += 8) {
        acc0 += a[k + 0] * W[(size_t)(k + 0) * N + j];
        acc1 += a[k + 1] * W[(size_t)(k + 1) * N + j];
        acc2 += a[k + 2] * W[(size_t)(k + 2) * N + j];
        acc3 += a[k + 3] * W[(size_t)(k + 3) * N + j];
        acc4 += a[k + 4] * W[(size_t)(k + 4) * N + j];
        acc5 += a[k + 5] * W[(size_t)(k + 5) * N + j];
        acc6 += a[k + 6] * W[(size_t)(k + 6) * N + j];
        acc7 += a[k + 7] * W[(size_t)(k + 7) * N + j];
    }
    C[(size_t)n * N + j] = ((acc0 + acc1) + (acc2 + acc3)) + ((acc4 + acc5) + (acc6 + acc7));
}

// ---------------- GAT attention scalars el/er ----------------
template<int NH, int OD>
__global__ void k_eler(const float* __restrict__ feat, const float* __restrict__ al,
                       const float* __restrict__ ar, float* __restrict__ el,
                       float* __restrict__ er)
{
    __shared__ float red[256];
    int n = blockIdx.x;
    for (int h = 0; h < NH; ++h) {
        float a = 0.f, b = 0.f;
        for (int k = threadIdx.x; k < OD; k += blockDim.x) {
            float f = feat[(size_t)n * NH * OD + h * OD + k];
            a += f * al[h * OD + k];
            b += f * ar[h * OD + k];
        }
        float sa = block_reduce_sum(a, red);
        float sb = block_reduce_sum(b, red);
        if (threadIdx.x == 0) { el[n * NH + h] = sa; er[n * NH + h] = sb; }
    }
}

// ---------------- GAT edge-softmax aggregation (one block per dst node) -------
template<int NH, int OD, int QN, int DO_ELU, int WLT>
__global__ void k_gat_agg(const float* __restrict__ feat,
                          const float* __restrict__ el, const float* __restrict__ er,
                          const int* __restrict__ esrc, const int* __restrict__ edst,
                          const float* __restrict__ bias, float* __restrict__ out,
                          float* __restrict__ labT)
{
    __shared__ float red[256];
    __shared__ int ss[NEDGE];
    __shared__ int dd[NEDGE];
    int n = blockIdx.x;
    for (int t = threadIdx.x; t < NEDGE; t += blockDim.x) { ss[t] = esrc[t]; dd[t] = edst[t]; }
    __syncthreads();
    float ern[NH], emax[NH], den[NH];
    #pragma unroll
    for (int h = 0; h < NH; ++h) ern[h] = er[n * NH + h];
    #pragma unroll
    for (int h = 0; h < NH; ++h) {
        float mx = -1e30f;
        for (int t = threadIdx.x; t < NEDGE; t += blockDim.x) {
            if (dd[t] == n) {
                float x = el[ss[t] * NH + h] + ern[h];
                x = x > 0.f ? x : 0.2f * x;
                mx = fmaxf(mx, x);
            }
        }
        emax[h] = block_reduce_max(mx, red);
        float sm = 0.f;
        for (int t = threadIdx.x; t < NEDGE; t += blockDim.x) {
            if (dd[t] == n) {
                float x = el[ss[t] * NH + h] + ern[h];
                x = x > 0.f ? x : 0.2f * x;
                sm += expf(x - emax[h]);
            }
        }
        den[h] = block_reduce_sum(sm, red);
    }
    float acc[QN];
    #pragma unroll
    for (int q = 0; q < QN; ++q) acc[q] = 0.f;
    for (int t = 0; t < NEDGE; ++t) {
        if (dd[t] != n) continue;
        int s = ss[t];
        float alpha[NH];
        #pragma unroll
        for (int h = 0; h < NH; ++h) {
            float x = el[s * NH + h] + ern[h];
            x = x > 0.f ? x : 0.2f * x;
            alpha[h] = expf(x - emax[h]) / (den[h] + 1e-9f);
        }
        #pragma unroll
        for (int q = 0; q < QN; ++q) {
            int idx = threadIdx.x + q * 256;
            if (idx < NH * OD) {
                int h = idx / OD;
                acc[q] += alpha[h] * feat[(size_t)s * NH * OD + idx];
            }
        }
    }
    #pragma unroll
    for (int q = 0; q < QN; ++q) {
        int idx = threadIdx.x + q * 256;
        if (idx < NH * OD) {
            float v = acc[q] + bias[idx];
            float o = DO_ELU ? (v > 0.f ? v : expm1f(v)) : v;
            out[(size_t)n * NH * OD + idx] = o;
            if (WLT) labT[(size_t)idx * NLAB + n] = o;
        }
    }
}

// ---------------- per-entity: EL = lnorm(ent_emb @ lab.T); F/G = EL @ lin2 ----
__global__ void __launch_bounds__(128) k_entlab(
    const float* __restrict__ ent_emb, const float* __restrict__ labT,
    const float* __restrict__ ln_g, const float* __restrict__ ln_b,
    const float* __restrict__ lin2_W,
    float* __restrict__ F, float* __restrict__ G)
{
    __shared__ float e[HIDD];
    __shared__ float red[128];
    __shared__ float elsh[NLAB];
    int be = blockIdx.x;                          // 0..191
    for (int k = threadIdx.x; k < HIDD; k += 128) e[k] = ent_emb[(size_t)be * HIDD + k];
    __syncthreads();
    int l = threadIdx.x;
    float a = 0.f;
    if (l < NLAB)
        for (int k = 0; k < HIDD; ++k) a += e[k] * labT[k * NLAB + l];
    float v = (l < NLAB) ? a : 0.f;
    float s  = block_reduce_sum(v, red);
    float s2 = block_reduce_sum(v * v, red);
    const float invL = 1.0f / NLAB;
    float mu = s * invL;
    float var = s2 * invL - mu * mu;
    float is = 1.0f / sqrtf(var + 1e-5f);
    if (l < NLAB) elsh[l] = (a - mu) * is * ln_g[l] + ln_b[l];
    __syncthreads();
    if (l < NLAB) {
        float f = 0.f, g = 0.f;
        for (int q = 0; q < NLAB; ++q) {
            float eq = elsh[q];
            f += eq * lin2_W[q * NLAB + l];
            g += eq * lin2_W[(NLAB + q) * NLAB + l];
        }
        F[be * NLAB + l] = f;
        G[be * NLAB + l] = g;
    }
}

// ---------------- ht rows -> bf16 HT; + emb_bf; + llhf gather -----------------
__global__ void __launch_bounds__(256) k_ht(
    const __hip_bfloat16* __restrict__ ent_attb, const int* __restrict__ hts,
    __hip_bfloat16* __restrict__ HTb,
    const float* __restrict__ ent_emb, __hip_bfloat16* __restrict__ emb_bf,
    const float* __restrict__ F, const float* __restrict__ G,
    const float* __restrict__ lin2_b, _Float16* __restrict__ llhf)
{
    __shared__ float red[256];
    int bid = blockIdx.x;
    if (bid >= NROW + 72) {
        // llhf gather: llhf[n,l] = F[h-ent,l] + G[t-ent,l] + lin2_b[l]
        int t = (bid - NROW - 72) * 256 + threadIdx.x;   // over 4000*128
        int n = t >> 7, l = t & 127;
        float v = 0.f;
        if (l < NLAB) {
            int b = n / NPAIR;
            int hi = hts[n * 2], ti = hts[n * 2 + 1];
            v = F[(b * NEENT + hi) * NLAB + l] + G[(b * NEENT + ti) * NLAB + l] + lin2_b[l];
        }
        llhf[t] = (_Float16)v;
        return;
    }
    if (bid >= NROW) {
        // ent_emb f32 -> bf16 row-major (72 blocks)
        int t = (bid - NROW) * 256 + threadIdx.x;   // over 18432
        const float4* p = (const float4*)(ent_emb + (size_t)t * 8);
        float4 a = p[0], b = p[1];
        short8v v;
        v[0] = (short)f2bfbits(a.x); v[1] = (short)f2bfbits(a.y);
        v[2] = (short)f2bfbits(a.z); v[3] = (short)f2bfbits(a.w);
        v[4] = (short)f2bfbits(b.x); v[5] = (short)f2bfbits(b.y);
        v[6] = (short)f2bfbits(b.z); v[7] = (short)f2bfbits(b.w);
        ((short8v*)emb_bf)[t] = v;
        return;
    }
    int n = (bid & 7) * 500 + (bid >> 3);        // XCD-group
    int b = n / NPAIR;
    int hi = hts[n * 2], ti = hts[n * 2 + 1];
    const __hip_bfloat16* ha = ent_attb + ((size_t)(b * NEENT + hi)) * NHEADS * SEQL;
    const __hip_bfloat16* ta = ent_attb + ((size_t)(b * NEENT + ti)) * NHEADS * SEQL;
    int s0 = threadIdx.x * 4;
    float4 acc = {0.f, 0.f, 0.f, 0.f};
    #pragma unroll
    for (int h = 0; h < NHEADS; ++h) {
        short4v a4 = *(const short4v*)&ha[h * SEQL + s0];
        short4v t4 = *(const short4v*)&ta[h * SEQL + s0];
        acc.x += bf2f(a4.x) * bf2f(t4.x);
        acc.y += bf2f(a4.y) * bf2f(t4.y);
        acc.z += bf2f(a4.z) * bf2f(t4.z);
        acc.w += bf2f(a4.w) * bf2f(t4.w);
    }
    const float inv12 = 1.0f / NHEADS;
    acc.x *= inv12; acc.y *= inv12; acc.z *= inv12; acc.w *= inv12;
    float Z = block_reduce_sum(acc.x + acc.y + acc.z + acc.w, red);
    float scale = 1.0f / (Z + 1e-5f);
    int nloc = n % NPAIR;
    short4v v;
    v.x = (short)f2bfbits(acc.x * scale);
    v.y = (short)f2bfbits(acc.y * scale);
    v.z = (short)f2bfbits(acc.z * scale);
    v.w = (short)f2bfbits(acc.w * scale);
    *(short4v*)&HTb[((size_t)b * 1024 + nloc) * SEQL + s0] = v;
}

// ---------------- rs = HT @ seq per doc via MFMA -> bf16 rsb (B prefetch) -----
__global__ void __launch_bounds__(256) k_rs_mfma(
    const __hip_bfloat16* __restrict__ HTb, const __hip_bfloat16* __restrict__ seqb,
    __hip_bfloat16* __restrict__ rsb)
{
    int b = blockIdx.x;
    int wg = (b & 7) * 96 + (b >> 3);           // doc-grouped per XCD
    int doc = wg / 192;
    int rem = wg % 192;
    int mtile = rem / 6, ngrp = rem % 6;
    int tid = threadIdx.x, wave = tid >> 6, lane = tid & 63;
    int mh = wave & 1, ng = wave >> 1;
    int lr = lane & 15, lg = lane >> 4;
    int rowl = mtile * 32 + mh * 16 + lr;
    const short8v* av = (const short8v*)(HTb + (((size_t)doc * 1024 + rowl) * SEQL));
    const short8v* bv = (const short8v*)seqb;
    int dtbase = ngrp * 8 + ng * 4;
    f32x4 acc[4];
    #pragma unroll
    for (int nt = 0; nt < 4; ++nt) acc[nt] = f32x4{0.f, 0.f, 0.f, 0.f};
    const short8v* wp0 = bv + ((((size_t)doc * 32) * 48 + dtbase) * 64 + lane);
    short8v bc[4];
    #pragma unroll
    for (int nt = 0; nt < 4; ++nt) bc[nt] = wp0[nt * 64];
    short8v ac = av[lg];
    for (int kt = 0; kt < 32; ++kt) {
        int ktn = kt < 31 ? kt + 1 : 31;
        const short8v* wpn = bv + ((((size_t)doc * 32 + ktn) * 48 + dtbase) * 64 + lane);
        short8v bn[4];
        #pragma unroll
        for (int nt = 0; nt < 4; ++nt) bn[nt] = wpn[nt * 64];
        short8v an = av[ktn * 4 + lg];
        #pragma unroll
        for (int nt = 0; nt < 4; ++nt)
            acc[nt] = __builtin_amdgcn_mfma_f32_16x16x32_bf16(ac, bc[nt], acc[nt], 0, 0, 0);
        ac = an;
        #pragma unroll
        for (int nt = 0; nt < 4; ++nt) bc[nt] = bn[nt];
    }
    #pragma unroll
    for (int nt = 0; nt < 4; ++nt) {
        int d = ngrp * 128 + ng * 64 + nt * 16 + lr;
        #pragma unroll
        for (int r = 0; r < 4; ++r) {
            int nloc = mtile * 32 + mh * 16 + lg * 4 + r;
            if (nloc < NPAIR)
                rsb[((size_t)(doc * NPAIR + nloc)) * HIDD + d] = __float2bfloat16(acc[nt][r]);
        }
    }
}

// ---------------- head+tail GEMM via MFMA, M=64, slice-contiguous bids --------
__global__ void __launch_bounds__(256) k_ht2_mfma(
    const __hip_bfloat16* __restrict__ emb_bf, const __hip_bfloat16* __restrict__ rsb,
    const int* __restrict__ hts,
    const __hip_bfloat16* __restrict__ Whb, const __hip_bfloat16* __restrict__ Wtb,
    const float* __restrict__ head_b, const float* __restrict__ tail_b,
    float* __restrict__ h2, float* __restrict__ t2)
{
    int bid = blockIdx.x;
    int sl = bid / NMT64;            // slice 0..11 (which,ngrp) — contiguous blocks
    int mtile = bid % NMT64;
    int which = sl / 6, ngrp = sl % 6;
    int tid = threadIdx.x, wave = tid >> 6, lane = tid & 63;
    int ng = wave & 1, mp = wave >> 1;
    int lr = lane & 15, lg = lane >> 4;
    int na = mtile * 64 + mp * 32 + lr;
    int nb = na + 16;
    int nac = na < NROW ? na : NROW - 1;
    int nbc = nb < NROW ? nb : NROW - 1;
    int ba = nac / NPAIR, bb = nbc / NPAIR;
    int enta = hts[nac * 2 + which];
    int entb = hts[nbc * 2 + which];
    const short8v* embrow_a = (const short8v*)emb_bf + (size_t)(ba * NEENT + enta) * 96;
    const short8v* embrow_b = (const short8v*)emb_bf + (size_t)(bb * NEENT + entb) * 96;
    const short8v* rsrow_a  = (const short8v*)rsb + (size_t)nac * 96;
    const short8v* rsrow_b  = (const short8v*)rsb + (size_t)nbc * 96;
    const short8v* wv = (const short8v*)(which ? Wtb : Whb);
    const float* bias = which ? tail_b : head_b;
    float* out = which ? t2 : h2;
    f32x4 acc[2][4];
    #pragma unroll
    for (int m = 0; m < 2; ++m)
        #pragma unroll
        for (int nt = 0; nt < 4; ++nt) acc[m][nt] = f32x4{0.f, 0.f, 0.f, 0.f};
    int ntbase = ngrp * 8 + ng * 4;
    short8v aca = embrow_a[lg], acb = embrow_b[lg];
    const short8v* wp0 = wv + ((size_t)(0 * 48 + ntbase) * 64 + lane);
    short8v bc[4];
    #pragma unroll
    for (int nt = 0; nt < 4; ++nt) bc[nt] = wp0[nt * 64];
    for (int kt = 0; kt < 48; ++kt) {
        int ktn = kt < 47 ? kt + 1 : 47;
        const short8v* pa = ktn < 24 ? embrow_a + ktn * 4 : rsrow_a + (ktn - 24) * 4;
        const short8v* pb = ktn < 24 ? embrow_b + ktn * 4 : rsrow_b + (ktn - 24) * 4;
        short8v ana = pa[lg];
        short8v anb = pb[lg];
        const short8v* wpn = wv + (((size_t)ktn * 48 + ntbase) * 64 + lane);
        short8v bn[4];
        #pragma unroll
        for (int nt = 0; nt < 4; ++nt) bn[nt] = wpn[nt * 64];
        #pragma unroll
        for (int nt = 0; nt < 4; ++nt) {
            acc[0][nt] = __builtin_amdgcn_mfma_f32_16x16x32_bf16(aca, bc[nt], acc[0][nt], 0, 0, 0);
            acc[1][nt] = __builtin_amdgcn_mfma_f32_16x16x32_bf16(acb, bc[nt], acc[1][nt], 0, 0, 0);
        }
        aca = ana; acb = anb;
        #pragma unroll
        for (int nt = 0; nt < 4; ++nt) bc[nt] = bn[nt];
    }
    #pragma unroll
    for (int m = 0; m < 2; ++m) {
        #pragma unroll
        for (int nt = 0; nt < 4; ++nt) {
            int col = ngrp * 128 + ng * 64 + nt * 16 + lr;
            float bj = bias[col];
            #pragma unroll
            for (int r = 0; r < 4; ++r) {
                int n2 = mtile * 64 + mp * 32 + m * 16 + lg * 4 + r;
                if (n2 < NROW)
                    out[(size_t)n2 * HIDD + col] = tanhf(acc[m][nt][r] + bj);
            }
        }
    }
}

// ---------------- bilinear fp16 MFMA, M=128, XCD-pinned chunks ----------------
// grid 768; xcd = bid&7 owns chunks [3*xcd, 3*xcd+2] (1.6MB Wb slice -> L2)
__global__ void __launch_bounds__(256) k_bilin_mfma(
    const float* __restrict__ h2, const float* __restrict__ t2,
    const _Float16* __restrict__ llhf, const _Float16* __restrict__ Wb,
    float* __restrict__ pout)
{
    __shared__ unsigned int hs2[BM * 68];   // {h,h} packed fp16 (all 64 i)
    __shared__ _Float16 ts[BM * 40];        // fp16 t, this j-half (32 + pad 8)
    int bid = blockIdx.x;
    int xcd = bid & 7;
    int idx8 = bid >> 3;                 // 0..95
    int chunk = xcd * 3 + idx8 % 3;      // 0..23, XCD-pinned
    int mtile = idx8 / 3;                // 0..31
    int c  = chunk >> 1;
    int jh = chunk & 1;
    int j0 = jh * 32;
    int n0 = mtile * BM;
    int tid = threadIdx.x;
    int wave = tid >> 6, lane = tid & 63;
    int ng = wave & 1, mp = wave >> 1;
    int lr = lane & 15;
    int lg = lane >> 4;
    int koff = lg << 3;
    int row0 = mp * 64 + lr;             // frags at row0 + 16*m, m=0..3
    f32x4 acc[4][4];
    #pragma unroll
    for (int m = 0; m < 4; ++m)
        #pragma unroll
        for (int nt = 0; nt < 4; ++nt) acc[m][nt] = f32x4{0.f, 0.f, 0.f, 0.f};

    const half8v* wbv = (const half8v*)Wb;

    for (int idx = tid; idx < BM * 64; idx += 256) {
        int r = idx >> 6, cc = idx & 63;
        float hv = h2[(size_t)(n0 + r) * HIDD + c * 64 + cc];
        unsigned short hb = __builtin_bit_cast(unsigned short, (_Float16)hv);
        hs2[r * 68 + cc] = ((unsigned int)hb << 16) | hb;
    }
    for (int idx = tid; idx < BM * 32; idx += 256) {
        int r = idx >> 5, cc = idx & 31;
        ts[r * 40 + cc] = (_Float16)t2[(size_t)(n0 + r) * HIDD + c * 64 + j0 + cc];
    }
    __syncthreads();

    half8v tv[4];
    #pragma unroll
    for (int m = 0; m < 4; ++m)
        tv[m] = *(const half8v*)&ts[(row0 + 16 * m) * 40 + koff];
    int ktbase = c * 128 + jh;
    const half8v* wpb = wbv + (((size_t)ktbase * 8 + ng * 4) * 64 + lane);  // +i*1024
    half8v bc[4];
    #pragma unroll
    for (int nt = 0; nt < 4; ++nt) bc[nt] = wpb[nt * 64];
    for (int i = 0; i < 64; ++i) {
        int in = i < 63 ? i + 1 : 63;
        const half8v* wpn = wpb + (size_t)in * 1024;
        half8v bn[4];
        #pragma unroll
        for (int nt = 0; nt < 4; ++nt) bn[nt] = wpn[nt * 64];
        half8v af[4];
        #pragma unroll
        for (int m = 0; m < 4; ++m) {
            unsigned int hh = hs2[(row0 + 16 * m) * 68 + i];
            af[m] = __builtin_bit_cast(half8v, uint4v{hh, hh, hh, hh}) * tv[m];
        }
        #pragma unroll
        for (int nt = 0; nt < 4; ++nt) {
            #pragma unroll
            for (int m = 0; m < 4; ++m)
                acc[m][nt] = __builtin_amdgcn_mfma_f32_16x16x32_f16(af[m], bc[nt], acc[m][nt], 0, 0, 0);
        }
        #pragma unroll
        for (int nt = 0; nt < 4; ++nt) bc[nt] = bn[nt];
    }
    if (chunk == NCHUNK - 1) {
        const half8v* lv = (const half8v*)llhf;
        #pragma unroll
        for (int tt = 0; tt < 4; ++tt) {
            int kt = KSTEPS_MAIN + tt;
            const half8v* wp = wbv + (((size_t)kt * 8 + ng * 4) * 64 + lane);
            half8v bf[4];
            #pragma unroll
            for (int nt = 0; nt < 4; ++nt) bf[nt] = wp[nt * 64];
            #pragma unroll
            for (int m = 0; m < 4; ++m) {
                half8v afm = lv[(size_t)(n0 + row0 + 16 * m) * 16 + tt * 4 + lg];
                #pragma unroll
                for (int nt = 0; nt < 4; ++nt)
                    acc[m][nt] = __builtin_amdgcn_mfma_f32_16x16x32_f16(afm, bf[nt], acc[m][nt], 0, 0, 0);
            }
        }
    }
    #pragma unroll
    for (int m = 0; m < 4; ++m) {
        #pragma unroll
        for (int nt = 0; nt < 4; ++nt) {
            int col = ng * 64 + nt * 16 + lr;
            if (col < NPOUT) {
                #pragma unroll
                for (int r = 0; r < 4; ++r) {
                    int rown = n0 + mp * 64 + m * 16 + lg * 4 + r;
                    if (rown < NROW)
                        pout[((size_t)chunk * NROW + rown) * NPOUT + col] = acc[m][nt][r];
                }
            }
        }
    }
}

// ---------------- reduce partials + bias -> out -------------------------------
__global__ void k_bilin_reduce(const float* __restrict__ pout,
                               const float* __restrict__ bil_b,
                               float* __restrict__ out)
{
    int t = blockIdx.x * 256 + threadIdx.x;
    if (t >= NROW * NLAB) return;
    int n = t / NLAB, l = t - n * NLAB;
    float a = bil_b[l];
    #pragma unroll
    for (int q = 0; q < NCHUNK; ++q) a += pout[((size_t)q * NROW + n) * NPOUT + l];
    out[t] = a;
}

extern "C" void kernel_launch(void* const* d_in, const int* in_sizes, int n_in,
                              void* d_out, int out_size, void* d_ws, size_t ws_size,
                              hipStream_t stream)
{
    (void)in_sizes; (void)n_in; (void)out_size; (void)ws_size;
    const float* seq       = (const float*)d_in[0];
    const float* att       = (const float*)d_in[1];
    const int*   mstarts   = (const int*)d_in[2];
    const int*   hts       = (const int*)d_in[4];
    const float* label_emb = (const float*)d_in[5];
    const float* gat_W0    = (const float*)d_in[6];
    const float* gat_al0   = (const float*)d_in[7];
    const float* gat_ar0   = (const float*)d_in[8];
    const float* gat_b0    = (const float*)d_in[9];
    const float* gat_W1    = (const float*)d_in[10];
    const float* gat_al1   = (const float*)d_in[11];
    const float* gat_ar1   = (const float*)d_in[12];
    const float* gat_b1    = (const float*)d_in[13];
    const int*   esrc      = (const int*)d_in[14];
    const int*   edst      = (const int*)d_in[15];
    const float* head_W    = (const float*)d_in[16];
    const float* head_b    = (const float*)d_in[17];
    const float* tail_W    = (const float*)d_in[18];
    const float* tail_b    = (const float*)d_in[19];
    const float* ln_g      = (const float*)d_in[20];
    const float* ln_b      = (const float*)d_in[21];
    const float* lin2_W    = (const float*)d_in[22];
    const float* lin2_b    = (const float*)d_in[23];
    const float* bil_W     = (const float*)d_in[24];
    const float* bil_b     = (const float*)d_in[25];
    float* out = (float*)d_out;

    // ws layout: no overlays, 64B-aligned
    float* p = (float*)d_ws;
    auto alloc = [&](size_t n) { float* r = p; p += ((n + 15) & ~(size_t)15); return r; };
    float* ent_emb = alloc(147456);
    float* F       = alloc(18624);
    float* G       = alloc(18624);
    float* labT    = alloc(74496);
    float* feat0   = alloc(97000);
    float* el0     = alloc(200);
    float* er0     = alloc(200);
    float* h0      = alloc(97000);
    float* feat1   = alloc(74496);
    float* el1     = alloc(104);
    float* er1     = alloc(104);
    float* lab     = alloc(74496);
    float* h2      = alloc((size_t)4096 * 768);
    float* t2      = alloc((size_t)4096 * 768);
    float* pout    = alloc((size_t)NCHUNK * NROW * NPOUT);
    __hip_bfloat16* ent_attb = (__hip_bfloat16*)alloc(1179648);  // 2359296 bf16
    __hip_bfloat16* HTb    = (__hip_bfloat16*)alloc(2097152);
    __hip_bfloat16* seqb   = (__hip_bfloat16*)alloc(1572864);
    __hip_bfloat16* rsb    = (__hip_bfloat16*)alloc(1536000);
    __hip_bfloat16* Whb    = (__hip_bfloat16*)alloc(589824);
    __hip_bfloat16* Wtb    = (__hip_bfloat16*)alloc(589824);
    __hip_bfloat16* emb_bf = (__hip_bfloat16*)alloc(73728);
    _Float16* llhf = (_Float16*)alloc(262144);   // 4096 x 128 fp16
    _Float16* Wb   = (_Float16*)alloc(3153920);

    // 1. all input-only preps + GAT L0 GEMM
    k_prep_all<<<PB_TOT, 256, 0, stream>>>(
        label_emb, gat_W0, feat0, bil_W, Wb, seq, seqb, mstarts, ent_emb,
        att, ent_attb, head_W, Whb, tail_W, Wtb);

    // GAT chain
    k_eler<2, 500><<<NLAB, 256, 0, stream>>>(feat0, gat_al0, gat_ar0, el0, er0);
    k_gat_agg<2, 500, 4, 1, 0><<<NLAB, 256, 0, stream>>>(feat0, el0, er0, esrc, edst, gat_b0, h0, nullptr);
    k_gemm2<1000, 768><<<NLAB * 3, 256, 0, stream>>>(h0, gat_W1, feat1);
    k_eler<1, 768><<<NLAB, 256, 0, stream>>>(feat1, gat_al1, gat_ar1, el1, er1);
    k_gat_agg<1, 768, 3, 0, 1><<<NLAB, 256, 0, stream>>>(feat1, el1, er1, esrc, edst, gat_b1, lab, labT);

    // per-entity label logits: lnorm + F/G in one kernel
    k_entlab<<<NDOC * NEENT, 128, 0, stream>>>(ent_emb, labT, ln_g, ln_b, lin2_W, F, G);

    // ht rows + emb_bf + llhf gather in one kernel
    k_ht<<<NROW + 72 + 2000, 256, 0, stream>>>(ent_attb, hts, HTb, ent_emb, emb_bf,
                                               F, G, lin2_b, llhf);

    k_rs_mfma<<<768, 256, 0, stream>>>(HTb, seqb, rsb);

    k_ht2_mfma<<<2 * NMT64 * 6, 256, 0, stream>>>(emb_bf, rsb, hts, Whb, Wtb, head_b, tail_b, h2, t2);

    k_bilin_mfma<<<NMT * NCHUNK, 256, 0, stream>>>(h2, t2, llhf, Wb, pout);
    k_bilin_reduce<<<(NROW * NLAB + 255) / 256, 256, 0, stream>>>(pout, bil_b, out);
}